// Round 1
// baseline (2108.143 us; speedup 1.0000x reference)
//
#include <hip/hip_runtime.h>
#include <math.h>

#define N_NODES 10000
#define IN_CH   256
#define HH      16
#define NCLASS  10
#define BN_EPS  1e-5f
#define NJ      160000          // N * H
#define NI      2500
#define NJ4     (NJ / 4)        // 40000
#define SPLIT_I 20
#define ROWS_PER_SPLIT (NI / SPLIT_I)  // 125

// ---------------- kernel 1: h = relu(x @ feat_W + feat_b) ----------------
__global__ void embed_kernel(const float* __restrict__ x,
                             const float* __restrict__ W,
                             const float* __restrict__ b,
                             float* __restrict__ h) {
    __shared__ float Ws[IN_CH * HH];      // 16 KB
    __shared__ float xs[16 * IN_CH];      // 16 KB
    int t = threadIdx.x;
    const float4* W4 = (const float4*)W;
    float4* Ws4 = (float4*)Ws;
    for (int i = t; i < IN_CH * HH / 4; i += 256) Ws4[i] = W4[i];
    int node0 = blockIdx.x * 16;
    const float4* x4 = (const float4*)(x + (size_t)node0 * IN_CH);
    float4* xs4 = (float4*)xs;
    for (int i = t; i < 16 * IN_CH / 4; i += 256) xs4[i] = x4[i];
    __syncthreads();
    int nl = t >> 4, col = t & 15;
    float acc = b[col];
    const float* xrow = xs + nl * IN_CH;
#pragma unroll 8
    for (int k = 0; k < IN_CH; ++k) acc += xrow[k] * Ws[k * HH + col];
    h[(node0 + nl) * HH + col] = fmaxf(acc, 0.f);
}

// ---------------- kernel 2: topo += g @ gll_W (split-K atomics) ----------
__global__ void topo_gemv(const float* __restrict__ g,
                          const float* __restrict__ Wt,
                          float* __restrict__ topo) {
    __shared__ float gs[ROWS_PER_SPLIT];
    int i0 = blockIdx.y * ROWS_PER_SPLIT;
    for (int i = threadIdx.x; i < ROWS_PER_SPLIT; i += blockDim.x)
        gs[i] = g[i0 + i];
    __syncthreads();
    int j4 = blockIdx.x * blockDim.x + threadIdx.x;
    if (j4 >= NJ4) return;
    const float4* W4 = (const float4*)Wt;
    const float4* p = W4 + (size_t)i0 * NJ4 + j4;
    float4 acc = {0.f, 0.f, 0.f, 0.f};
#pragma unroll 5
    for (int i = 0; i < ROWS_PER_SPLIT; ++i) {
        float gv = gs[i];
        float4 w = p[(size_t)i * NJ4];
        acc.x += gv * w.x; acc.y += gv * w.y;
        acc.z += gv * w.z; acc.w += gv * w.w;
    }
    float* o = topo + (size_t)j4 * 4;
    atomicAdd(o + 0, acc.x);
    atomicAdd(o + 1, acc.y);
    atomicAdd(o + 2, acc.z);
    atomicAdd(o + 3, acc.w);
}

// ---------------- kernel 3: CSR row_ptr via binary search ----------------
__global__ void build_rowptr(const int* __restrict__ r1, int e1,
                             const int* __restrict__ r2, int e2,
                             int* __restrict__ rp1, int* __restrict__ rp2) {
    int t = blockIdx.x * blockDim.x + threadIdx.x;
    const int* arr; int E; int* out; int target;
    if (t < N_NODES + 1)            { arr = r1; E = e1; out = rp1; target = t; }
    else if (t < 2 * (N_NODES + 1)) { arr = r2; E = e2; out = rp2; target = t - (N_NODES + 1); }
    else return;
    int lo = 0, hi = E;
    while (lo < hi) {
        int mid = (lo + hi) >> 1;
        if (arr[mid] < target) lo = mid + 1; else hi = mid;
    }
    out[target] = lo;
}

// ---------------- kernel 4: conv0 (spmm x2, F=16) + BatchNorm ------------
__global__ void conv0_bn(const float* __restrict__ h,
                         const int* __restrict__ c1idx, const float* __restrict__ v1,
                         const int* __restrict__ c2idx, const float* __restrict__ v2,
                         const int* __restrict__ rp1, const int* __restrict__ rp2,
                         const float* __restrict__ gamma, const float* __restrict__ beta,
                         const float* __restrict__ mean, const float* __restrict__ var,
                         float* __restrict__ c1bn) {
    int r = blockIdx.x;
    int lane = threadIdx.x;
    int es = lane >> 4, col = lane & 15;
    float acc1 = 0.f, acc2 = 0.f;
    int s = rp1[r], e = rp1[r + 1];
    for (int k = s + es; k < e; k += 4)
        acc1 += v1[k] * h[(size_t)c1idx[k] * HH + col];
    s = rp2[r]; e = rp2[r + 1];
    for (int k = s + es; k < e; k += 4)
        acc2 += v2[k] * h[(size_t)c2idx[k] * HH + col];
    acc1 += __shfl_xor(acc1, 16); acc1 += __shfl_xor(acc1, 32);
    acc2 += __shfl_xor(acc2, 16); acc2 += __shfl_xor(acc2, 32);
    if (es == 0) {
        int ch1 = col, ch2 = col + 16;
        float o1 = (acc1 - mean[ch1]) * rsqrtf(var[ch1] + BN_EPS) * gamma[ch1] + beta[ch1];
        float o2 = (acc2 - mean[ch2]) * rsqrtf(var[ch2] + BN_EPS) * gamma[ch2] + beta[ch2];
        c1bn[r * 32 + ch1] = o1;
        c1bn[r * 32 + ch2] = o2;
    }
}

// ---------------- kernel 5: conv1 (spmm x2, F=32) ------------------------
__global__ void conv1_k(const float* __restrict__ c1bn,
                        const int* __restrict__ c1idx, const float* __restrict__ v1,
                        const int* __restrict__ c2idx, const float* __restrict__ v2,
                        const int* __restrict__ rp1, const int* __restrict__ rp2,
                        float* __restrict__ c2) {
    int r = blockIdx.x;
    int lane = threadIdx.x;
    int es = lane >> 5, col = lane & 31;
    float acc1 = 0.f, acc2 = 0.f;
    int s = rp1[r], e = rp1[r + 1];
    for (int k = s + es; k < e; k += 2)
        acc1 += v1[k] * c1bn[(size_t)c1idx[k] * 32 + col];
    s = rp2[r]; e = rp2[r + 1];
    for (int k = s + es; k < e; k += 2)
        acc2 += v2[k] * c1bn[(size_t)c2idx[k] * 32 + col];
    acc1 += __shfl_xor(acc1, 32);
    acc2 += __shfl_xor(acc2, 32);
    if (es == 0) {
        c2[r * 64 + col] = acc1;
        c2[r * 64 + 32 + col] = acc2;
    }
}

// ---------------- kernel 6: concat -> [128x10] matmul -> log_softmax -----
__global__ void final_k(const float* __restrict__ h,
                        const float* __restrict__ c1bn,
                        const float* __restrict__ c2,
                        const float* __restrict__ topo,
                        const float* __restrict__ gll_b,
                        const float* __restrict__ fW,
                        const float* __restrict__ fb,
                        float* __restrict__ out) {
    __shared__ float Ws[128 * NCLASS];   // 5 KB
    __shared__ float bs[NCLASS];
    int t = threadIdx.x;
    for (int i = t; i < 128 * NCLASS; i += 256) Ws[i] = fW[i];
    if (t < NCLASS) bs[t] = fb[t];
    __syncthreads();
    int r = blockIdx.x * 256 + t;
    if (r >= N_NODES) return;
    float acc[NCLASS];
#pragma unroll
    for (int c = 0; c < NCLASS; ++c) acc[c] = bs[c];
    // xs0 [16]
    for (int k = 0; k < 16; ++k) {
        float v = h[r * 16 + k];
#pragma unroll
        for (int c = 0; c < NCLASS; ++c) acc[c] += v * Ws[k * NCLASS + c];
    }
    // c1bn [32] at offset 16
    for (int k = 0; k < 32; ++k) {
        float v = c1bn[r * 32 + k];
#pragma unroll
        for (int c = 0; c < NCLASS; ++c) acc[c] += v * Ws[(16 + k) * NCLASS + c];
    }
    // c2 [64] at offset 48
    for (int k = 0; k < 64; ++k) {
        float v = c2[r * 64 + k];
#pragma unroll
        for (int c = 0; c < NCLASS; ++c) acc[c] += v * Ws[(48 + k) * NCLASS + c];
    }
    // topo [16] at offset 112 (+ gll_b, added once here)
    for (int k = 0; k < 16; ++k) {
        float v = topo[r * 16 + k] + gll_b[r * 16 + k];
#pragma unroll
        for (int c = 0; c < NCLASS; ++c) acc[c] += v * Ws[(112 + k) * NCLASS + c];
    }
    float m = acc[0];
#pragma unroll
    for (int c = 1; c < NCLASS; ++c) m = fmaxf(m, acc[c]);
    float ssum = 0.f;
#pragma unroll
    for (int c = 0; c < NCLASS; ++c) ssum += expf(acc[c] - m);
    float lse = logf(ssum) + m;
#pragma unroll
    for (int c = 0; c < NCLASS; ++c) out[r * NCLASS + c] = acc[c] - lse;
}

extern "C" void kernel_launch(void* const* d_in, const int* in_sizes, int n_in,
                              void* d_out, int out_size, void* d_ws, size_t ws_size,
                              hipStream_t stream) {
    const float* x        = (const float*)d_in[0];
    const float* gwc_feat = (const float*)d_in[1];
    const int*   a1_row   = (const int*)  d_in[2];
    const int*   a1_col   = (const int*)  d_in[3];
    const float* a1_val   = (const float*)d_in[4];
    const int*   a2_row   = (const int*)  d_in[5];
    const int*   a2_col   = (const int*)  d_in[6];
    const float* a2_val   = (const float*)d_in[7];
    const float* feat_W   = (const float*)d_in[8];
    const float* feat_b   = (const float*)d_in[9];
    const float* gll_W    = (const float*)d_in[10];
    const float* gll_b    = (const float*)d_in[11];
    const float* bn_gamma = (const float*)d_in[12];
    const float* bn_beta  = (const float*)d_in[13];
    const float* bn_mean  = (const float*)d_in[14];
    const float* bn_var   = (const float*)d_in[15];
    const float* fin_W    = (const float*)d_in[16];
    const float* fin_b    = (const float*)d_in[17];
    float* out = (float*)d_out;

    const int E1 = in_sizes[2];
    const int E2 = in_sizes[5];

    // workspace layout (floats, then ints)
    float* h    = (float*)d_ws;                       // N*16
    float* topo = h + N_NODES * 16;                   // N*16
    float* c1bn = topo + N_NODES * 16;                // N*32
    float* c2   = c1bn + N_NODES * 32;                // N*64
    int*   rp1  = (int*)(c2 + N_NODES * 64);          // N+1
    int*   rp2  = rp1 + (N_NODES + 16);               // N+1 (padded)

    // zero the topo accumulator (ws is poisoned before every call)
    hipMemsetAsync(topo, 0, N_NODES * 16 * sizeof(float), stream);

    // 1. feature embed
    embed_kernel<<<N_NODES / 16, 256, 0, stream>>>(x, feat_W, feat_b, h);

    // 2. topo GEMV (1.6 GB read — the dominant kernel)
    dim3 g2((NJ4 + 255) / 256, SPLIT_I);
    topo_gemv<<<g2, 256, 0, stream>>>(gwc_feat, gll_W, topo);

    // 3. CSR offsets for both adjacency lists
    build_rowptr<<<(2 * (N_NODES + 1) + 255) / 256, 256, 0, stream>>>(
        a1_row, E1, a2_row, E2, rp1, rp2);

    // 4. conv0 + BN
    conv0_bn<<<N_NODES, 64, 0, stream>>>(h, a1_col, a1_val, a2_col, a2_val,
                                         rp1, rp2, bn_gamma, bn_beta,
                                         bn_mean, bn_var, c1bn);

    // 5. conv1
    conv1_k<<<N_NODES, 64, 0, stream>>>(c1bn, a1_col, a1_val, a2_col, a2_val,
                                        rp1, rp2, c2);

    // 6. final projection + log_softmax
    final_k<<<(N_NODES + 255) / 256, 256, 0, stream>>>(
        h, c1bn, c2, topo, gll_b, fin_W, fin_b, out);
}